// Round 2
// baseline (466.596 us; speedup 1.0000x reference)
//
#include <hip/hip_runtime.h>

// NMS 3x3, replicate pad, strict >, max seeded at 0 (center tap zeroed).
// x: (8, 32, 512, 512) fp32. out = x * (x > max(0, 8 neighbors)).
//
// Pure-streaming design: one wave owns a full 512-wide row and streams a
// 64-row chunk. Lane l holds cols [8l, 8l+8) as 2x float4 (32 B/lane loads).
// Vertical 3-row window lives in registers (rolling hmax); horizontal
// neighbors are in-register within a lane and __shfl at lane seams.
// No LDS, no __syncthreads, ~3% halo re-read (2 rows per 64-row chunk).
// Replicate padding via clamped row index / clamped seam columns: the
// clamped neighbor equals the center, so strict > fails -> border = 0,
// exactly matching the reference.

#define IMG_W 512
#define IMG_H 512
#define NPLANES 256          // 8 * 32
#define CHUNK 64             // rows per wave-task
#define THREADS 256          // 4 waves per block
#define WAVES_PER_BLOCK (THREADS / 64)
#define CHUNKS_PER_PLANE (IMG_H / CHUNK)

typedef float v4f __attribute__((ext_vector_type(4)));  // native vector for nontemporal

static_assert(IMG_W == 64 * 8, "one wave covers a full row at 8 floats/lane");
static_assert(IMG_H % CHUNK == 0, "chunks divide evenly");

__device__ __forceinline__ void load_row(const float* __restrict__ base, int r,
                                         float d[8]) {
    const v4f a = *(const v4f*)(base + (size_t)r * IMG_W);
    const v4f b = *(const v4f*)(base + (size_t)r * IMG_W + 4);
    d[0] = a.x; d[1] = a.y; d[2] = a.z; d[3] = a.w;
    d[4] = b.x; d[5] = b.y; d[6] = b.z; d[7] = b.w;
}

// lr[i] = max(left_i, right_i)  (center excluded); hm[i] = max(l,c,r).
__device__ __forceinline__ void row_stats(const float d[8], int lane,
                                          float lr[8], float hm[8]) {
    float lnb = __shfl_up(d[7], 1);          // lane-1's col 8l-1
    lnb = (lane == 0) ? d[0] : lnb;          // replicate col 0
    float rnb = __shfl_down(d[0], 1);        // lane+1's col 8l+8
    rnb = (lane == 63) ? d[7] : rnb;         // replicate col 511

    lr[0] = fmaxf(lnb,  d[1]);
    lr[1] = fmaxf(d[0], d[2]);
    lr[2] = fmaxf(d[1], d[3]);
    lr[3] = fmaxf(d[2], d[4]);
    lr[4] = fmaxf(d[3], d[5]);
    lr[5] = fmaxf(d[4], d[6]);
    lr[6] = fmaxf(d[5], d[7]);
    lr[7] = fmaxf(d[6], rnb);
#pragma unroll
    for (int i = 0; i < 8; ++i) hm[i] = fmaxf(lr[i], d[i]);
}

__global__ __launch_bounds__(THREADS)
void nms3x3_kernel(const float* __restrict__ x, float* __restrict__ out) {
    const int wid   = blockIdx.x * WAVES_PER_BLOCK + (threadIdx.x >> 6);
    const int lane  = threadIdx.x & 63;
    const int plane = wid / CHUNKS_PER_PLANE;
    const int chunk = wid % CHUNKS_PER_PLANE;
    const int r0    = chunk * CHUNK;

    const float* img  = x   + (size_t)plane * IMG_H * IMG_W + lane * 8;
    float*       oimg = out + (size_t)plane * IMG_H * IMG_W + lane * 8;

    float pd[8], cd[8], nd[8];
    float pHm[8], cLr[8], cHm[8], nLr[8], nHm[8];
    float junk[8];

    // Prologue: row r0-1 (clamped) -> pHm; row r0 -> cd/cLr/cHm.
    load_row(img, (r0 > 0) ? r0 - 1 : 0, pd);
    row_stats(pd, lane, junk, pHm);
    load_row(img, r0, cd);
    row_stats(cd, lane, cLr, cHm);

    for (int k = 0; k < CHUNK; ++k) {
        const int r  = r0 + k;
        const int rn = (r + 1 < IMG_H) ? r + 1 : IMG_H - 1;
        load_row(img, rn, nd);
        row_stats(nd, lane, nLr, nHm);

        float o[8];
#pragma unroll
        for (int i = 0; i < 8; ++i) {
            float m = fmaxf(fmaxf(pHm[i], nHm[i]), cLr[i]);
            m = fmaxf(m, 0.0f);                       // center tap zeroed
            o[i] = (cd[i] > m) ? cd[i] : 0.0f;
        }

        v4f oa = { o[0], o[1], o[2], o[3] };
        v4f ob = { o[4], o[5], o[6], o[7] };
        __builtin_nontemporal_store(oa, (v4f*)(oimg + (size_t)r * IMG_W));
        __builtin_nontemporal_store(ob, (v4f*)(oimg + (size_t)r * IMG_W + 4));

#pragma unroll
        for (int i = 0; i < 8; ++i) {
            pHm[i] = cHm[i];
            cd[i]  = nd[i];
            cLr[i] = nLr[i];
            cHm[i] = nHm[i];
        }
    }
}

extern "C" void kernel_launch(void* const* d_in, const int* in_sizes, int n_in,
                              void* d_out, int out_size, void* d_ws, size_t ws_size,
                              hipStream_t stream) {
    const float* x = (const float*)d_in[0];
    float* out     = (float*)d_out;
    const int total_waves = NPLANES * CHUNKS_PER_PLANE;        // 2048
    dim3 grid(total_waves / WAVES_PER_BLOCK);                  // 512 blocks
    nms3x3_kernel<<<grid, dim3(THREADS), 0, stream>>>(x, out);
}